// Round 1
// baseline (255.901 us; speedup 1.0000x reference)
//
#include <hip/hip_runtime.h>

#define E_TOT 1048576
#define LOGITS 917504

typedef short bf16x8 __attribute__((ext_vector_type(8)));
typedef float f32x4 __attribute__((ext_vector_type(4)));
typedef unsigned short u16;
typedef unsigned int u32;

#define DEV static __device__ __forceinline__

DEV u16 f2bf(float f){ u32 u = __float_as_uint(f); return (u16)((u + 0x7fffu + ((u>>16)&1u))>>16); }
DEV float bf2f(u16 h){ return __uint_as_float(((u32)h)<<16); }
DEV u32 pack2(float a, float b){ return (u32)f2bf(a) | ((u32)f2bf(b)<<16); }
DEV void unpack8(uint4 u, float* f){
  f[0]=__uint_as_float(u.x<<16); f[1]=__uint_as_float(u.x&0xffff0000u);
  f[2]=__uint_as_float(u.y<<16); f[3]=__uint_as_float(u.y&0xffff0000u);
  f[4]=__uint_as_float(u.z<<16); f[5]=__uint_as_float(u.z&0xffff0000u);
  f[6]=__uint_as_float(u.w<<16); f[7]=__uint_as_float(u.w&0xffff0000u);
}
DEV uint4 pack8(const float* f){
  uint4 u; u.x=pack2(f[0],f[1]); u.y=pack2(f[2],f[3]); u.z=pack2(f[4],f[5]); u.w=pack2(f[6],f[7]); return u;
}

// workspace element offsets (u16 units)
#define GNN_E   0          // 4*2*128*128      = 131072
#define EXT_E   131072     // 8*256*128        = 262144
#define POL1_E  393216     // 8*256*128        = 262144
#define POL2_E  655360     // 8*128*64(pad)    = 65536
#define HUB_E   720896     // 128*128          = 16384
#define VW1T_E  737280     // 128*128          = 16384
#define POOL_E  753664     // B*8*256          = 4194304  (head_emb aliases cols 0..127)
#define CTX_E   4947968    // B*128            = 262144
// total = 5210112 u16 = 10,420,224 bytes

// ---------------- weight packing into MFMA fragment order ----------------
__global__ __launch_bounds__(256) void pack_w(
    const float* __restrict__ Wself, const float* __restrict__ Wnbr,
    const float* __restrict__ extW,  const float* __restrict__ polW1,
    const float* __restrict__ polW2, const float* __restrict__ hubW,
    const float* __restrict__ valW1, u16* __restrict__ ws)
{
  int idx = blockIdx.x*256 + threadIdx.x;
  if (idx < 131072){                       // GNN W_self/W_nbr: [l][m][kb4][ct8][lane][j]
    int l = idx>>15, r = idx&32767;
    int m = (r>>14)&1, r2 = r&16383;
    int kb=(r2>>12)&3, ct=(r2>>9)&7, lane=(r2>>3)&63, j=r2&7;
    int k = kb*32 + ((lane>>4)<<3) + j, n = (ct<<4)+(lane&15);
    const float* W = m? Wnbr : Wself;
    ws[GNN_E+idx] = f2bf(W[(l<<14)+(k<<7)+n]);
  } else if (idx < 655360){                // extW / polW1: [h][kb8][ct8][lane][j]
    int i = idx - 131072;
    int isPol = (i >= 262144); if (isPol) i -= 262144;
    int h = i>>15, r = i&32767;
    int kb=(r>>12)&7, ct=(r>>9)&7, lane=(r>>3)&63, j=r&7;
    int k = kb*32 + ((lane>>4)<<3) + j, n = (ct<<4)+(lane&15);
    const float* W = isPol? polW1 : extW;
    ws[(isPol?POL1_E:EXT_E)+i] = f2bf(W[(h<<15)+(k<<7)+n]);
  } else if (idx < 720896){                // polW2 padded 56->64: [h][kb4][ct4][lane][j]
    int i = idx - 655360;
    int h = i>>13, r = i&8191;
    int kb=(r>>11)&3, ct=(r>>9)&3, lane=(r>>3)&63, j=r&7;
    int k = kb*32+((lane>>4)<<3)+j, n=(ct<<4)+(lane&15);
    float v = (n<56)? polW2[h*7168 + k*56 + n] : 0.0f;
    ws[POL2_E+i] = f2bf(v);
  } else if (idx < 737280){                // hubW: [kb4][ct8][lane][j]
    int i = idx-720896;
    int kb=(i>>12)&3, ct=(i>>9)&7, lane=(i>>3)&63, j=i&7;
    int k = kb*32+((lane>>4)<<3)+j, n=(ct<<4)+(lane&15);
    ws[HUB_E+i] = f2bf(hubW[(k<<7)+n]);
  } else if (idx < 753664){                // valW1 transposed: [c][k]
    int i = idx-737280;
    int c = i>>7, k = i&127;
    ws[VW1T_E+i] = f2bf(valW1[(k<<7)+c]);
  }
}

// ---------------- fused per-graph GNN + pooling + value head ----------------
__global__ __launch_bounds__(256) void gnn_kernel(
  const float* __restrict__ x, const int* __restrict__ ei,
  const int* __restrict__ subsets, const float* __restrict__ W_in,
  const float* __restrict__ b_in, const float* __restrict__ b_enc,
  const float* __restrict__ val_b1, const float* __restrict__ val_W2,
  const float* __restrict__ val_b2,
  const u16* __restrict__ packGNN, const u16* __restrict__ valW1T,
  u16* __restrict__ pooled, float* __restrict__ out)
{
  __shared__ __align__(16) u16 h_bf[8192];    // [64][128] bf16, XOR-swizzled
  __shared__ __align__(16) u16 agg_bf[8192];  // same; aliased as f32 stage early
  __shared__ u16 csr[512];
  __shared__ u16 indptr[66];
  __shared__ float deg_inv[64];
  __shared__ u32 cnt[64];
  __shared__ float redbuf[4];

  int t = threadIdx.x, b = blockIdx.x;
  int lane = t & 63, wv = t >> 6;

  // ---- edge preprocessing: counts, prefix, CSR ----
  int e0 = (b<<9) + (t<<1);
  int s0 = ei[e0]&63,        s1 = ei[e0+1]&63;
  int d0 = ei[E_TOT+e0]&63,  d1 = ei[E_TOT+e0+1]&63;
  if (t<64) cnt[t] = 0;
  __syncthreads();
  atomicAdd(&cnt[d0],1u); atomicAdd(&cnt[d1],1u);
  __syncthreads();
  if (t<64){
    int v = (int)cnt[t], inc = v;
    #pragma unroll
    for (int d=1; d<64; d<<=1){ int o = __shfl_up(inc,d); if (lane>=d) inc += o; }
    indptr[t] = (u16)(inc-v);
    if (t==63) indptr[64] = (u16)inc;
    deg_inv[t] = 1.0f/(float)(v>0?v:1);
  }
  __syncthreads();
  if (t<64) cnt[t]=0;
  __syncthreads();
  { u32 p = (u32)indptr[d0] + atomicAdd(&cnt[d0],1u); csr[p]=(u16)s0;
    u32 q = (u32)indptr[d1] + atomicAdd(&cnt[d1],1u); csr[q]=(u16)s1; }

  // ---- stage x and W_in into agg area (f32) ----
  float* stagef = (float*)agg_bf;
  { const float* xg = x + (b<<10);
    for (int i=t;i<1024;i+=256) stagef[i]=xg[i];
    for (int i=t;i<2048;i+=256) stagef[1024+i]=W_in[i];
  }
  __syncthreads();

  // ---- h0 = relu(x @ W_in + b_in) ----
  {
    int row=t>>2, q=t&3, c0=q<<5;
    float acc[32];
    #pragma unroll
    for (int i=0;i<32;i++) acc[i]=b_in[c0+i];
    for (int k=0;k<16;k++){
      float xv = stagef[(row<<4)+k];
      const float* wr = &stagef[1024+(k<<7)+c0];
      #pragma unroll
      for (int i=0;i<32;i++) acc[i] = fmaf(xv, wr[i], acc[i]);
    }
    int sw=row&7;
    #pragma unroll
    for (int c=0;c<4;c++){
      float v[8];
      #pragma unroll
      for (int i=0;i<8;i++) v[i] = fmaxf(acc[(c<<3)+i],0.0f);
      *(uint4*)&h_bf[(row<<7)+((((q<<2)+c)^sw)<<3)] = pack8(v);
    }
  }
  __syncthreads();

  // ---- 4 GNN layers ----
  #pragma unroll 1
  for (int l=0;l<4;l++){
    // aggregation: thread = (dst, 32-col chunk); f32 accumulate, /deg, -> bf16 LDS
    {
      int dst=t>>2, q=t&3;
      float a[32];
      #pragma unroll
      for (int i=0;i<32;i++) a[i]=0.0f;
      int ee = indptr[dst+1];
      for (int e=indptr[dst]; e<ee; e++){
        int src = csr[e]; int base = src<<7; int sw = src&7;
        #pragma unroll
        for (int c=0;c<4;c++){
          uint4 u = *(const uint4*)&h_bf[base + ((((q<<2)+c)^sw)<<3)];
          float f[8]; unpack8(u,f);
          #pragma unroll
          for (int i=0;i<8;i++) a[(c<<3)+i]+=f[i];
        }
      }
      float di = deg_inv[dst];
      int sw=dst&7;
      #pragma unroll
      for (int c=0;c<4;c++){
        float v[8];
        #pragma unroll
        for (int i=0;i<8;i++) v[i]=a[(c<<3)+i]*di;
        *(uint4*)&agg_bf[(dst<<7)+((((q<<2)+c)^sw)<<3)] = pack8(v);
      }
    }
    __syncthreads();
    // MFMA: h_new = relu(h@Wself + agg@Wnbr + b_enc)
    {
      const u16* pl = packGNN + (l<<15);
      int ctb = wv<<1, r15=lane&15, kh=lane>>4;
      bf16x8 bs[4][2], bn[4][2];
      #pragma unroll
      for (int kb=0;kb<4;kb++){
        #pragma unroll
        for (int cc=0;cc<2;cc++){
          bs[kb][cc] = *(const bf16x8*)&pl[(kb<<12)+((ctb+cc)<<9)+(lane<<3)];
          bn[kb][cc] = *(const bf16x8*)&pl[16384+(kb<<12)+((ctb+cc)<<9)+(lane<<3)];
        }
      }
      f32x4 zero4 = {0.0f,0.0f,0.0f,0.0f};
      f32x4 acc[4][2];
      #pragma unroll
      for (int rt=0;rt<4;rt++){ acc[rt][0]=zero4; acc[rt][1]=zero4; }
      #pragma unroll
      for (int kb=0;kb<4;kb++){
        int ch = (kb<<2)+kh;
        #pragma unroll
        for (int rt=0;rt<4;rt++){
          int row=(rt<<4)+r15;
          bf16x8 af = *(const bf16x8*)&h_bf[(row<<7)+((ch^(row&7))<<3)];
          acc[rt][0]=__builtin_amdgcn_mfma_f32_16x16x32_bf16(af,bs[kb][0],acc[rt][0],0,0,0);
          acc[rt][1]=__builtin_amdgcn_mfma_f32_16x16x32_bf16(af,bs[kb][1],acc[rt][1],0,0,0);
        }
        #pragma unroll
        for (int rt=0;rt<4;rt++){
          int row=(rt<<4)+r15;
          bf16x8 ag = *(const bf16x8*)&agg_bf[(row<<7)+((ch^(row&7))<<3)];
          acc[rt][0]=__builtin_amdgcn_mfma_f32_16x16x32_bf16(ag,bn[kb][0],acc[rt][0],0,0,0);
          acc[rt][1]=__builtin_amdgcn_mfma_f32_16x16x32_bf16(ag,bn[kb][1],acc[rt][1],0,0,0);
        }
      }
      float be[2];
      be[0] = b_enc[(l<<7)+(wv<<5)+r15];
      be[1] = b_enc[(l<<7)+(wv<<5)+16+r15];
      __syncthreads();   // all LDS reads of h_bf/agg_bf complete
      #pragma unroll
      for (int rt=0;rt<4;rt++){
        #pragma unroll
        for (int cc=0;cc<2;cc++){
          int col=(wv<<5)+(cc<<4)+r15;
          #pragma unroll
          for (int i=0;i<4;i++){
            int row=(rt<<4)+(kh<<2)+i;
            float v = fmaxf(acc[rt][cc][i]+be[cc],0.0f);
            h_bf[(row<<7)+(((col>>3)^(row&7))<<3)+(col&7)] = f2bf(v);
          }
        }
      }
    }
    __syncthreads();
  }

  // ---- pooling: per head mean/max over its 8 subset nodes ----
  if (t<64) cnt[t] = (u32)subsets[t];
  __syncthreads();
  {
    int hd=t>>5, q=t&31, cb=q<<2;
    float ms[4]={0,0,0,0}, mx[4]={-3e38f,-3e38f,-3e38f,-3e38f};
    #pragma unroll
    for (int s=0;s<8;s++){
      int row = (int)cnt[(hd<<3)+s];
      int ch = cb>>3, sw=row&7;
      uint2 u = *(const uint2*)&h_bf[(row<<7)+((ch^sw)<<3)+(cb&7)];
      float f0=__uint_as_float(u.x<<16), f1=__uint_as_float(u.x&0xffff0000u);
      float f2=__uint_as_float(u.y<<16), f3=__uint_as_float(u.y&0xffff0000u);
      ms[0]+=f0; ms[1]+=f1; ms[2]+=f2; ms[3]+=f3;
      mx[0]=fmaxf(mx[0],f0); mx[1]=fmaxf(mx[1],f1);
      mx[2]=fmaxf(mx[2],f2); mx[3]=fmaxf(mx[3],f3);
    }
    int base = (((b<<3)+hd)<<8);
    uint2 um, ux;
    um.x = pack2(ms[0]*0.125f, ms[1]*0.125f); um.y = pack2(ms[2]*0.125f, ms[3]*0.125f);
    ux.x = pack2(mx[0],mx[1]);                ux.y = pack2(mx[2],mx[3]);
    *(uint2*)&pooled[base+cb]      = um;
    *(uint2*)&pooled[base+128+cb]  = ux;
  }
  __syncthreads();

  // ---- value head: gm = mean over 64 nodes; v = tanh(relu(gm@W1+b1)@W2+b2) ----
  if (t<128){
    float s=0;
    for (int row=0;row<64;row++)
      s += bf2f(h_bf[(row<<7)+(((t>>3)^(row&7))<<3)+(t&7)]);
    stagef[t] = s*0.015625f;
  }
  __syncthreads();
  if (t<128){
    float acc = val_b1[t];
    const u16* wr = &valW1T[t<<7];
    #pragma unroll 8
    for (int k=0;k<128;k++) acc = fmaf(stagef[k], bf2f(wr[k]), acc);
    float contrib = fmaxf(acc,0.0f)*val_W2[t];
    #pragma unroll
    for (int d=1; d<64; d<<=1) contrib += __shfl_xor(contrib,d);
    if (lane==0) redbuf[wv]=contrib;
  }
  __syncthreads();
  if (t==0) out[LOGITS+b] = tanhf(redbuf[0]+redbuf[1]+val_b2[0]);
}

// ---------------- head kernel 1: z = pooled@extW + b, LayerNorm, relu ----------------
__global__ __launch_bounds__(256) void head1_kernel(
  u16* __restrict__ pooled, const u16* __restrict__ packExt,
  const float* __restrict__ ext_b, const float* __restrict__ ln_g,
  const float* __restrict__ ln_b)
{
  __shared__ __align__(16) u16 A_lds[16384];   // [64][256] bf16 swizzled
  __shared__ float zf[8448];                   // [64][132] f32
  int t=threadIdx.x, gb=blockIdx.x, hd=blockIdx.y;
  int lane=t&63, wv=t>>6;
  for (int i=t;i<2048;i+=256){
    int row=i>>5, ch=i&31;
    uint4 u = *(const uint4*)&pooled[(((((gb<<6)+row)<<3)+hd)<<8)+(ch<<3)];
    *(uint4*)&A_lds[(row<<8)+((ch^(row&7))<<3)] = u;
  }
  __syncthreads();
  const u16* pw = packExt + (hd<<15);
  int ctb=wv<<1, r15=lane&15, kh=lane>>4;
  bf16x8 bfw[8][2];
  #pragma unroll
  for (int kb=0;kb<8;kb++){
    #pragma unroll
    for (int cc=0;cc<2;cc++)
      bfw[kb][cc] = *(const bf16x8*)&pw[(kb<<12)+((ctb+cc)<<9)+(lane<<3)];
  }
  f32x4 zero4 = {0.0f,0.0f,0.0f,0.0f};
  f32x4 acc[4][2];
  #pragma unroll
  for (int rt=0;rt<4;rt++){ acc[rt][0]=zero4; acc[rt][1]=zero4; }
  #pragma unroll
  for (int kb=0;kb<8;kb++){
    int ch=(kb<<2)+kh;
    #pragma unroll
    for (int rt=0;rt<4;rt++){
      int row=(rt<<4)+r15;
      bf16x8 a = *(const bf16x8*)&A_lds[(row<<8)+((ch^(row&7))<<3)];
      acc[rt][0]=__builtin_amdgcn_mfma_f32_16x16x32_bf16(a,bfw[kb][0],acc[rt][0],0,0,0);
      acc[rt][1]=__builtin_amdgcn_mfma_f32_16x16x32_bf16(a,bfw[kb][1],acc[rt][1],0,0,0);
    }
  }
  float eb[2]={ext_b[(hd<<7)+(wv<<5)+r15], ext_b[(hd<<7)+(wv<<5)+16+r15]};
  #pragma unroll
  for (int rt=0;rt<4;rt++){
    #pragma unroll
    for (int cc=0;cc<2;cc++){
      int col=(wv<<5)+(cc<<4)+r15;
      #pragma unroll
      for (int i=0;i<4;i++){
        int row=(rt<<4)+(kh<<2)+i;
        zf[row*132+col]=acc[rt][cc][i]+eb[cc];
      }
    }
  }
  __syncthreads();
  // LayerNorm over 128 cols, 4 threads/row
  int row=t>>2, q=t&3;
  const float* zr=&zf[row*132+(q<<5)];
  float s=0, ss=0;
  #pragma unroll 8
  for (int i=0;i<32;i++){ float v=zr[i]; s+=v; ss+=v*v; }
  s += __shfl_xor(s,1); ss += __shfl_xor(ss,1);
  s += __shfl_xor(s,2); ss += __shfl_xor(ss,2);
  float mu=s*0.0078125f, var=ss*0.0078125f-mu*mu;
  float rstd=rsqrtf(var+1e-5f);
  int ob=(((((gb<<6)+row)<<3)+hd)<<8)+(q<<5);
  const float* g =&ln_g[(hd<<7)+(q<<5)];
  const float* bb=&ln_b[(hd<<7)+(q<<5)];
  #pragma unroll
  for (int i=0;i<32;i+=2){
    float e0=fmaxf((zr[i]  -mu)*rstd*g[i]  +bb[i],  0.0f);
    float e1=fmaxf((zr[i+1]-mu)*rstd*g[i+1]+bb[i+1],0.0f);
    *(u32*)&pooled[ob+i] = pack2(e0,e1);   // head_emb aliases pooled cols 0..127
  }
}

// ---------------- head kernel 2: ctx = relu(mean_h(head_emb) @ hubW + b) ----------------
__global__ __launch_bounds__(256) void ctx_kernel(
  const u16* __restrict__ pooled, const u16* __restrict__ packHub,
  const float* __restrict__ hub_b, u16* __restrict__ ctx)
{
  __shared__ __align__(16) u16 m_lds[8192];
  int t=threadIdx.x, gb=blockIdx.x, lane=t&63, wv=t>>6;
  for (int i=t;i<1024;i+=256){
    int row=i>>4, ch=i&15;
    float a8[8]={0,0,0,0,0,0,0,0};
    #pragma unroll
    for (int h=0;h<8;h++){
      uint4 u = *(const uint4*)&pooled[(((((gb<<6)+row)<<3)+h)<<8)+(ch<<3)];
      float f[8]; unpack8(u,f);
      #pragma unroll
      for (int k=0;k<8;k++) a8[k]+=f[k];
    }
    #pragma unroll
    for (int k=0;k<8;k++) a8[k]*=0.125f;
    *(uint4*)&m_lds[(row<<7)+((ch^(row&7))<<3)] = pack8(a8);
  }
  __syncthreads();
  int ctb=wv<<1, r15=lane&15, kh=lane>>4;
  bf16x8 bh[4][2];
  #pragma unroll
  for (int kb=0;kb<4;kb++){
    #pragma unroll
    for (int cc=0;cc<2;cc++)
      bh[kb][cc] = *(const bf16x8*)&packHub[(kb<<12)+((ctb+cc)<<9)+(lane<<3)];
  }
  f32x4 zero4 = {0.0f,0.0f,0.0f,0.0f};
  f32x4 acc[4][2];
  #pragma unroll
  for (int rt=0;rt<4;rt++){ acc[rt][0]=zero4; acc[rt][1]=zero4; }
  #pragma unroll
  for (int kb=0;kb<4;kb++){
    int ch=(kb<<2)+kh;
    #pragma unroll
    for (int rt=0;rt<4;rt++){
      int row=(rt<<4)+r15;
      bf16x8 a = *(const bf16x8*)&m_lds[(row<<7)+((ch^(row&7))<<3)];
      acc[rt][0]=__builtin_amdgcn_mfma_f32_16x16x32_bf16(a,bh[kb][0],acc[rt][0],0,0,0);
      acc[rt][1]=__builtin_amdgcn_mfma_f32_16x16x32_bf16(a,bh[kb][1],acc[rt][1],0,0,0);
    }
  }
  float hb[2]={hub_b[(wv<<5)+r15], hub_b[(wv<<5)+16+r15]};
  #pragma unroll
  for (int rt=0;rt<4;rt++){
    #pragma unroll
    for (int cc=0;cc<2;cc++){
      int col=(wv<<5)+(cc<<4)+r15;
      #pragma unroll
      for (int i=0;i<4;i++){
        int row=(rt<<4)+(kh<<2)+i;
        ctx[(((gb<<6)+row)<<7)+col] = f2bf(fmaxf(acc[rt][cc][i]+hb[cc],0.0f));
      }
    }
  }
}

// ---------------- head kernel 3: hh = relu([he|ctx]@polW1+b1); logits = hh@polW2+b2 ----------------
__global__ __launch_bounds__(256) void pol_kernel(
  const u16* __restrict__ pooled, const u16* __restrict__ ctx,
  const u16* __restrict__ packPol1, const u16* __restrict__ packPol2,
  const float* __restrict__ pol_b1, const float* __restrict__ pol_b2,
  float* __restrict__ out)
{
  __shared__ __align__(16) u16 A_lds[16384];
  __shared__ __align__(16) u16 hh[8192];
  int t=threadIdx.x, gb=blockIdx.x, hd=blockIdx.y, lane=t&63, wv=t>>6;
  for (int i=t;i<2048;i+=256){
    int row=i>>5, ch=i&31;
    uint4 u;
    if (ch<16) u = *(const uint4*)&pooled[(((((gb<<6)+row)<<3)+hd)<<8)+(ch<<3)];
    else       u = *(const uint4*)&ctx[(((gb<<6)+row)<<7)+((ch-16)<<3)];
    *(uint4*)&A_lds[(row<<8)+((ch^(row&7))<<3)] = u;
  }
  __syncthreads();
  const u16* pw = packPol1 + (hd<<15);
  int ctb=wv<<1, r15=lane&15, kh=lane>>4;
  bf16x8 bw[8][2];
  #pragma unroll
  for (int kb=0;kb<8;kb++){
    #pragma unroll
    for (int cc=0;cc<2;cc++)
      bw[kb][cc] = *(const bf16x8*)&pw[(kb<<12)+((ctb+cc)<<9)+(lane<<3)];
  }
  f32x4 zero4 = {0.0f,0.0f,0.0f,0.0f};
  f32x4 acc[4][2];
  #pragma unroll
  for (int rt=0;rt<4;rt++){ acc[rt][0]=zero4; acc[rt][1]=zero4; }
  #pragma unroll
  for (int kb=0;kb<8;kb++){
    int ch=(kb<<2)+kh;
    #pragma unroll
    for (int rt=0;rt<4;rt++){
      int row=(rt<<4)+r15;
      bf16x8 a = *(const bf16x8*)&A_lds[(row<<8)+((ch^(row&7))<<3)];
      acc[rt][0]=__builtin_amdgcn_mfma_f32_16x16x32_bf16(a,bw[kb][0],acc[rt][0],0,0,0);
      acc[rt][1]=__builtin_amdgcn_mfma_f32_16x16x32_bf16(a,bw[kb][1],acc[rt][1],0,0,0);
    }
  }
  float pb[2]={pol_b1[(hd<<7)+(wv<<5)+r15], pol_b1[(hd<<7)+(wv<<5)+16+r15]};
  #pragma unroll
  for (int rt=0;rt<4;rt++){
    #pragma unroll
    for (int cc=0;cc<2;cc++){
      int col=(wv<<5)+(cc<<4)+r15;
      #pragma unroll
      for (int i=0;i<4;i++){
        int row=(rt<<4)+(kh<<2)+i;
        float v = fmaxf(acc[rt][cc][i]+pb[cc],0.0f);
        hh[(row<<7)+(((col>>3)^(row&7))<<3)+(col&7)] = f2bf(v);
      }
    }
  }
  __syncthreads();
  // GEMM2: [64x128] @ [128x64(pad)], wave wv owns col tile wv
  const u16* p2 = packPol2 + (hd<<13);
  bf16x8 b2[4];
  #pragma unroll
  for (int kb=0;kb<4;kb++)
    b2[kb] = *(const bf16x8*)&p2[(kb<<11)+(wv<<9)+(lane<<3)];
  f32x4 a2[4];
  #pragma unroll
  for (int rt=0;rt<4;rt++) a2[rt]=zero4;
  #pragma unroll
  for (int kb=0;kb<4;kb++){
    int ch=(kb<<2)+kh;
    #pragma unroll
    for (int rt=0;rt<4;rt++){
      int row=(rt<<4)+r15;
      bf16x8 a = *(const bf16x8*)&hh[(row<<7)+((ch^(row&7))<<3)];
      a2[rt]=__builtin_amdgcn_mfma_f32_16x16x32_bf16(a,b2[kb],a2[rt],0,0,0);
    }
  }
  int col=(wv<<4)+r15;
  if (col<56){
    float pb2 = pol_b2[hd*56+col];
    #pragma unroll
    for (int rt=0;rt<4;rt++){
      #pragma unroll
      for (int i=0;i<4;i++){
        int row=(rt<<4)+(kh<<2)+i;
        out[(((((gb<<6)+row)<<3)+hd)*56)+col] = a2[rt][i]+pb2;
      }
    }
  }
}

extern "C" void kernel_launch(void* const* d_in, const int* in_sizes, int n_in,
                              void* d_out, int out_size, void* d_ws, size_t ws_size,
                              hipStream_t stream)
{
  const float* x     =(const float*)d_in[0];
  const int*   ei    =(const int*)  d_in[1];
  const int*   subs  =(const int*)  d_in[3];
  const float* W_in  =(const float*)d_in[4];
  const float* b_in  =(const float*)d_in[5];
  const float* W_self=(const float*)d_in[6];
  const float* W_nbr =(const float*)d_in[7];
  const float* b_enc =(const float*)d_in[8];
  const float* extW  =(const float*)d_in[9];
  const float* ext_b =(const float*)d_in[10];
  const float* ln_g  =(const float*)d_in[11];
  const float* ln_b  =(const float*)d_in[12];
  const float* hubW  =(const float*)d_in[13];
  const float* hub_b =(const float*)d_in[14];
  const float* polW1 =(const float*)d_in[15];
  const float* pol_b1=(const float*)d_in[16];
  const float* polW2 =(const float*)d_in[17];
  const float* pol_b2=(const float*)d_in[18];
  const float* valW1 =(const float*)d_in[19];
  const float* val_b1=(const float*)d_in[20];
  const float* valW2 =(const float*)d_in[21];
  const float* val_b2=(const float*)d_in[22];
  float* out=(float*)d_out;
  u16* ws=(u16*)d_ws;

  pack_w<<<2944,256,0,stream>>>(W_self,W_nbr,extW,polW1,polW2,hubW,valW1,ws);
  gnn_kernel<<<2048,256,0,stream>>>(x,ei,subs,W_in,b_in,b_enc,val_b1,valW2,val_b2,
      ws+GNN_E, ws+VW1T_E, ws+POOL_E, out);
  head1_kernel<<<dim3(32,8),256,0,stream>>>(ws+POOL_E, ws+EXT_E, ext_b, ln_g, ln_b);
  ctx_kernel<<<32,256,0,stream>>>(ws+POOL_E, ws+HUB_E, hub_b, ws+CTX_E);
  pol_kernel<<<dim3(32,8),256,0,stream>>>(ws+POOL_E, ws+CTX_E, ws+POL1_E, ws+POL2_E,
      pol_b1, pol_b2, out);
}

// Round 2
// 218.157 us; speedup vs baseline: 1.1730x; 1.1730x over previous
//
#include <hip/hip_runtime.h>

#define E_TOT 1048576
#define LOGITS 917504

typedef short bf16x8 __attribute__((ext_vector_type(8)));
typedef float f32x4 __attribute__((ext_vector_type(4)));
typedef unsigned short u16;
typedef unsigned int u32;

#define DEV static __device__ __forceinline__

DEV u16 f2bf(float f){ u32 u = __float_as_uint(f); return (u16)((u + 0x7fffu + ((u>>16)&1u))>>16); }
DEV float bf2f(u16 h){ return __uint_as_float(((u32)h)<<16); }
DEV u32 pack2(float a, float b){ return (u32)f2bf(a) | ((u32)f2bf(b)<<16); }
DEV void unpack8(uint4 u, float* f){
  f[0]=__uint_as_float(u.x<<16); f[1]=__uint_as_float(u.x&0xffff0000u);
  f[2]=__uint_as_float(u.y<<16); f[3]=__uint_as_float(u.y&0xffff0000u);
  f[4]=__uint_as_float(u.z<<16); f[5]=__uint_as_float(u.z&0xffff0000u);
  f[6]=__uint_as_float(u.w<<16); f[7]=__uint_as_float(u.w&0xffff0000u);
}
DEV uint4 pack8(const float* f){
  uint4 u; u.x=pack2(f[0],f[1]); u.y=pack2(f[2],f[3]); u.z=pack2(f[4],f[5]); u.w=pack2(f[6],f[7]); return u;
}

// workspace element offsets (u16 units)
#define GNN_E   0          // 4*2*128*128      = 131072
#define EXT_E   131072     // 8*256*128        = 262144
#define POL1_E  393216     // 8*256*128        = 262144
#define POL2_E  655360     // 8*128*64(pad)    = 65536
#define HUB_E   720896     // 128*128          = 16384
#define VW1T_E  737280     // 128*128          = 16384
#define POOL_E  753664     // B*8*256          = 4194304
#define CTX_E   4947968    // B*128 = 262144; first 4096 double as packed W_in
                           // (gnn reads W_in before ctx_kernel overwrites - stream ordered)

// ---------------- weight packing into MFMA fragment order ----------------
__global__ __launch_bounds__(256) void pack_w(
    const float* __restrict__ Wself, const float* __restrict__ Wnbr,
    const float* __restrict__ extW,  const float* __restrict__ polW1,
    const float* __restrict__ polW2, const float* __restrict__ hubW,
    const float* __restrict__ valW1, const float* __restrict__ W_in,
    u16* __restrict__ ws)
{
  int idx = blockIdx.x*256 + threadIdx.x;
  if (idx < 131072){                       // GNN W_self/W_nbr: [l][m][kb4][ct8][lane][j]
    int l = idx>>15, r = idx&32767;
    int m = (r>>14)&1, r2 = r&16383;
    int kb=(r2>>12)&3, ct=(r2>>9)&7, lane=(r2>>3)&63, j=r2&7;
    int k = kb*32 + ((lane>>4)<<3) + j, n = (ct<<4)+(lane&15);
    const float* W = m? Wnbr : Wself;
    ws[GNN_E+idx] = f2bf(W[(l<<14)+(k<<7)+n]);
  } else if (idx < 655360){                // extW / polW1: [h][kb8][ct8][lane][j]
    int i = idx - 131072;
    int isPol = (i >= 262144); if (isPol) i -= 262144;
    int h = i>>15, r = i&32767;
    int kb=(r>>12)&7, ct=(r>>9)&7, lane=(r>>3)&63, j=r&7;
    int k = kb*32 + ((lane>>4)<<3) + j, n = (ct<<4)+(lane&15);
    const float* W = isPol? polW1 : extW;
    ws[(isPol?POL1_E:EXT_E)+i] = f2bf(W[(h<<15)+(k<<7)+n]);
  } else if (idx < 720896){                // polW2 padded 56->64: [h][kb4][ct4][lane][j]
    int i = idx - 655360;
    int h = i>>13, r = i&8191;
    int kb=(r>>11)&3, ct=(r>>9)&3, lane=(r>>3)&63, j=r&7;
    int k = kb*32+((lane>>4)<<3)+j, n=(ct<<4)+(lane&15);
    float v = (n<56)? polW2[h*7168 + k*56 + n] : 0.0f;
    ws[POL2_E+i] = f2bf(v);
  } else if (idx < 737280){                // hubW: [kb4][ct8][lane][j]
    int i = idx-720896;
    int kb=(i>>12)&3, ct=(i>>9)&7, lane=(i>>3)&63, j=i&7;
    int k = kb*32+((lane>>4)<<3)+j, n=(ct<<4)+(lane&15);
    ws[HUB_E+i] = f2bf(hubW[(k<<7)+n]);
  } else if (idx < 753664){                // valW1 transposed: [c][k]
    int i = idx-737280;
    int c = i>>7, k = i&127;
    ws[VW1T_E+i] = f2bf(valW1[(k<<7)+c]);
  } else if (idx < 757760){                // W_in padded K 16->32: [ct8][lane][j]
    int i = idx-753664;
    int ct=(i>>9)&7, lane=(i>>3)&63, j=i&7;
    int k=((lane>>4)<<3)+j, n=(ct<<4)+(lane&15);
    float v = (k<16)? W_in[(k<<7)+n] : 0.0f;
    ws[CTX_E+i] = f2bf(v);
  }
}

// shared epilogue: acc[4][2] -> relu(acc+bias) -> h_bf (row-major) + ht (col-major)
DEV void epi_write(u16* h_bf, u16* ht, f32x4 (&acc)[4][2], float b0, float b1,
                   int wv, int r15, int kh)
{
  float bias[2] = {b0, b1};
  #pragma unroll
  for (int rt=0;rt<4;rt++){
    int sch = (rt<<1)+(kh>>1);               // node-chunk for ht writes
    int r0  = (rt<<4)+(kh<<2);
    #pragma unroll
    for (int cc=0;cc<2;cc++){
      int col=(wv<<5)+(cc<<4)+r15;
      float v0=fmaxf(acc[rt][cc][0]+bias[cc],0.0f);
      float v1=fmaxf(acc[rt][cc][1]+bias[cc],0.0f);
      float v2=fmaxf(acc[rt][cc][2]+bias[cc],0.0f);
      float v3=fmaxf(acc[rt][cc][3]+bias[cc],0.0f);
      int chc=(col>>3);
      h_bf[((r0+0)<<7)+(((chc^((r0+0)&7))<<3)|(col&7))]=f2bf(v0);
      h_bf[((r0+1)<<7)+(((chc^((r0+1)&7))<<3)|(col&7))]=f2bf(v1);
      h_bf[((r0+2)<<7)+(((chc^((r0+2)&7))<<3)|(col&7))]=f2bf(v2);
      h_bf[((r0+3)<<7)+(((chc^((r0+3)&7))<<3)|(col&7))]=f2bf(v3);
      uint2 w; w.x=pack2(v0,v1); w.y=pack2(v2,v3);
      *(uint2*)&ht[(col<<6)+(((sch^(col&7))<<3)|((kh&1)<<2))]=w;
    }
  }
}

// ---------------- fused per-graph GNN + pooling + value head ----------------
__global__ __launch_bounds__(256,3) void gnn_kernel(
  const float* __restrict__ x, const int* __restrict__ ei,
  const int* __restrict__ subsets, const float* __restrict__ b_in,
  const float* __restrict__ b_enc, const float* __restrict__ val_b1,
  const float* __restrict__ val_W2, const float* __restrict__ val_b2,
  const u16* __restrict__ packGNN, const u16* __restrict__ packWIN,
  const u16* __restrict__ valW1T,
  u16* __restrict__ pooled, float* __restrict__ out)
{
  __shared__ __align__(16) u16 h_bf[8192];    // h  [64 node][128 dim] swizzled
  __shared__ __align__(16) u16 ht[8192];      // hT [128 dim][64 node] swizzled; alias: u32 cnt[4096]
  __shared__ __align__(16) u16 agg_bf[8192];  // agg [64][128] swizzled; alias: x tile + f32 stage
  __shared__ float deg_inv[64];
  __shared__ int subs_s[64];
  __shared__ float redbuf[4];

  int t=threadIdx.x, b=blockIdx.x;
  int lane=t&63, wv=t>>6, r15=lane&15, kh=lane>>4, ctb=wv<<1;
  u32* cnt=(u32*)ht;
  f32x4 zero4={0.0f,0.0f,0.0f,0.0f};

  // ---- edges + count matrix (swizzled [dst][src]) ----
  int e0=(b<<9)+(t<<1);
  int2 sp=*(const int2*)&ei[e0];
  int2 dp=*(const int2*)&ei[E_TOT+e0];
  int s0=sp.x&63, s1=sp.y&63, d0=dp.x&63, d1=dp.y&63;
  if (t<64) subs_s[t]=subsets[t];
  for (int i=t;i<1024;i+=256) ((uint4*)cnt)[i]=make_uint4(0,0,0,0);
  __syncthreads();
  atomicAdd(&cnt[(d0<<6)+((((s0>>3)^(d0&7))<<3)|(s0&7))],1u);
  atomicAdd(&cnt[(d1<<6)+((((s1>>3)^(d1&7))<<3)|(s1&7))],1u);
  __syncthreads();
  if (t<64){
    u32 s=0;
    for (int k2=0;k2<16;k2++){ uint4 v=((uint4*)cnt)[(t<<4)+k2]; s+=v.x+v.y+v.z+v.w; }
    deg_inv[t]=1.0f/(float)(s>0u?s:1u);
  }
  __syncthreads();

  // ---- adjacency^T B-fragments in registers: adjf[ct][kb], A^T[src][dst]=cnt/deg ----
  bf16x8 adjf[4][2];
  #pragma unroll
  for (int ct=0;ct<4;ct++){
    int dst=(ct<<4)+r15; float di=deg_inv[dst];
    #pragma unroll
    for (int kb=0;kb<2;kb++){
      int cb=(kb<<2)+kh;
      const u32* p=&cnt[(dst<<6)+((cb^(dst&7))<<3)];
      uint4 lo=*(const uint4*)p, hi=*(const uint4*)(p+4);
      bf16x8 v;
      v[0]=(short)f2bf((float)lo.x*di); v[1]=(short)f2bf((float)lo.y*di);
      v[2]=(short)f2bf((float)lo.z*di); v[3]=(short)f2bf((float)lo.w*di);
      v[4]=(short)f2bf((float)hi.x*di); v[5]=(short)f2bf((float)hi.y*di);
      v[6]=(short)f2bf((float)hi.z*di); v[7]=(short)f2bf((float)hi.w*di);
      adjf[ct][kb]=v;
    }
  }
  // ---- stage x as bf16 [64][32] (K padded) into agg area ----
  u16* xb=agg_bf;
  { const float* xg=x+(b<<10);
    for (int i=t;i<2048;i+=256){
      int row=i>>5, col=i&31;
      float v=(col<16)? xg[(row<<4)+col] : 0.0f;
      xb[(row<<5)+((((col>>3)^(row&3))<<3)|(col&7))]=f2bf(v);
    }
  }
  __syncthreads();

  // ---- h0 = relu(x @ W_in + b_in) via MFMA ----
  {
    bf16x8 bw0=*(const bf16x8*)&packWIN[(ctb<<9)+(lane<<3)];
    bf16x8 bw1=*(const bf16x8*)&packWIN[((ctb+1)<<9)+(lane<<3)];
    f32x4 acc[4][2];
    #pragma unroll
    for (int rt=0;rt<4;rt++){ acc[rt][0]=zero4; acc[rt][1]=zero4; }
    #pragma unroll
    for (int rt=0;rt<4;rt++){
      int row=(rt<<4)+r15;
      bf16x8 af=*(const bf16x8*)&xb[(row<<5)+((kh^(row&3))<<3)];
      acc[rt][0]=__builtin_amdgcn_mfma_f32_16x16x32_bf16(af,bw0,acc[rt][0],0,0,0);
      acc[rt][1]=__builtin_amdgcn_mfma_f32_16x16x32_bf16(af,bw1,acc[rt][1],0,0,0);
    }
    float bi0=b_in[(wv<<5)+r15], bi1=b_in[(wv<<5)+16+r15];
    epi_write(h_bf,ht,acc,bi0,bi1,wv,r15,kh);
  }
  __syncthreads();

  // ---- 4 GNN layers ----
  #pragma unroll 1
  for (int l=0;l<4;l++){
    // weight fragments (global, L2-hot) - issue early
    const u16* pl = packGNN + (l<<15);
    bf16x8 bs[4][2], bn[4][2];
    #pragma unroll
    for (int kb=0;kb<4;kb++){
      #pragma unroll
      for (int cc=0;cc<2;cc++){
        bs[kb][cc] = *(const bf16x8*)&pl[(kb<<12)+((ctb+cc)<<9)+(lane<<3)];
        bn[kb][cc] = *(const bf16x8*)&pl[16384+(kb<<12)+((ctb+cc)<<9)+(lane<<3)];
      }
    }
    // aggT[dim][node] = hT @ adjT : wave owns dim tiles (ctb,ctb+1), all node tiles
    f32x4 a2[2][4];
    #pragma unroll
    for (int rt=0;rt<2;rt++){ a2[rt][0]=zero4; a2[rt][1]=zero4; a2[rt][2]=zero4; a2[rt][3]=zero4; }
    #pragma unroll
    for (int kb=0;kb<2;kb++){
      #pragma unroll
      for (int rt=0;rt<2;rt++){
        int dim=((ctb+rt)<<4)+r15;
        bf16x8 af=*(const bf16x8*)&ht[(dim<<6)+((((kb<<2)+kh)^(dim&7))<<3)];
        #pragma unroll
        for (int ct=0;ct<4;ct++)
          a2[rt][ct]=__builtin_amdgcn_mfma_f32_16x16x32_bf16(af,adjf[ct][kb],a2[rt][ct],0,0,0);
      }
    }
    #pragma unroll
    for (int rt=0;rt<2;rt++){
      int dch=((ctb+rt)<<1)+(kh>>1);
      #pragma unroll
      for (int ct=0;ct<4;ct++){
        int node=(ct<<4)+r15;
        uint2 w; w.x=pack2(a2[rt][ct][0],a2[rt][ct][1]); w.y=pack2(a2[rt][ct][2],a2[rt][ct][3]);
        *(uint2*)&agg_bf[(node<<7)+(((dch^(node&7))<<3)|((kh&1)<<2))]=w;
      }
    }
    __syncthreads();
    // h_new = relu(h@Wself + agg@Wnbr + b_enc)
    f32x4 acc[4][2];
    #pragma unroll
    for (int rt=0;rt<4;rt++){ acc[rt][0]=zero4; acc[rt][1]=zero4; }
    #pragma unroll
    for (int kb=0;kb<4;kb++){
      int ch=(kb<<2)+kh;
      #pragma unroll
      for (int rt=0;rt<4;rt++){
        int row=(rt<<4)+r15;
        bf16x8 af=*(const bf16x8*)&h_bf[(row<<7)+((ch^(row&7))<<3)];
        acc[rt][0]=__builtin_amdgcn_mfma_f32_16x16x32_bf16(af,bs[kb][0],acc[rt][0],0,0,0);
        acc[rt][1]=__builtin_amdgcn_mfma_f32_16x16x32_bf16(af,bs[kb][1],acc[rt][1],0,0,0);
      }
      #pragma unroll
      for (int rt=0;rt<4;rt++){
        int row=(rt<<4)+r15;
        bf16x8 ag=*(const bf16x8*)&agg_bf[(row<<7)+((ch^(row&7))<<3)];
        acc[rt][0]=__builtin_amdgcn_mfma_f32_16x16x32_bf16(ag,bn[kb][0],acc[rt][0],0,0,0);
        acc[rt][1]=__builtin_amdgcn_mfma_f32_16x16x32_bf16(ag,bn[kb][1],acc[rt][1],0,0,0);
      }
    }
    float be0=b_enc[(l<<7)+(wv<<5)+r15], be1=b_enc[(l<<7)+(wv<<5)+16+r15];
    __syncthreads();   // all LDS reads done before epilogue overwrites h/ht
    epi_write(h_bf,ht,acc,be0,be1,wv,r15,kh);
    __syncthreads();
  }

  // ---- pooling: per head mean/max over its 8 subset nodes ----
  {
    int hd=t>>5, q=t&31, cb=q<<2;
    float ms[4]={0,0,0,0}, mx[4]={-3e38f,-3e38f,-3e38f,-3e38f};
    int ch=cb>>3;
    #pragma unroll
    for (int s=0;s<8;s++){
      int row=subs_s[(hd<<3)+s]; int sw=row&7;
      uint2 u=*(const uint2*)&h_bf[(row<<7)+(((ch^sw)<<3)|(cb&7))];
      float f0=__uint_as_float(u.x<<16), f1=__uint_as_float(u.x&0xffff0000u);
      float f2=__uint_as_float(u.y<<16), f3=__uint_as_float(u.y&0xffff0000u);
      ms[0]+=f0; ms[1]+=f1; ms[2]+=f2; ms[3]+=f3;
      mx[0]=fmaxf(mx[0],f0); mx[1]=fmaxf(mx[1],f1);
      mx[2]=fmaxf(mx[2],f2); mx[3]=fmaxf(mx[3],f3);
    }
    int base=(((b<<3)+hd)<<8);
    uint2 um,ux;
    um.x=pack2(ms[0]*0.125f,ms[1]*0.125f); um.y=pack2(ms[2]*0.125f,ms[3]*0.125f);
    ux.x=pack2(mx[0],mx[1]);               ux.y=pack2(mx[2],mx[3]);
    *(uint2*)&pooled[base+cb]    =um;
    *(uint2*)&pooled[base+128+cb]=ux;
  }
  __syncthreads();

  // ---- value head ----
  float* stagef=(float*)agg_bf;
  if (t<128){
    float s=0;
    for (int row=0;row<64;row++)
      s += bf2f(h_bf[(row<<7)+((((t>>3)^(row&7))<<3)|(t&7))]);
    stagef[t]=s*0.015625f;
  }
  __syncthreads();
  if (t<128){
    float acc=val_b1[t];
    const u16* wr=&valW1T[t<<7];
    #pragma unroll 8
    for (int k=0;k<128;k++) acc=fmaf(stagef[k],bf2f(wr[k]),acc);
    float contrib=fmaxf(acc,0.0f)*val_W2[t];
    #pragma unroll
    for (int d=1;d<64;d<<=1) contrib+=__shfl_xor(contrib,d);
    if (lane==0) redbuf[wv]=contrib;
  }
  __syncthreads();
  if (t==0) out[LOGITS+b]=tanhf(redbuf[0]+redbuf[1]+val_b2[0]);
}

// ---------------- head 1: z = pooled@extW + b, LayerNorm, relu (16 graphs/block) ----------------
__global__ __launch_bounds__(256) void head1_kernel(
  u16* __restrict__ pooled, const u16* __restrict__ packExt,
  const float* __restrict__ ext_b, const float* __restrict__ ln_g,
  const float* __restrict__ ln_b)
{
  __shared__ __align__(16) u16 A_lds[4096];   // [16][256] swizzled
  __shared__ float zf[16*132];
  int t=threadIdx.x, gb=blockIdx.x, hd=blockIdx.y;
  int lane=t&63, wv=t>>6, r15=lane&15, kh=lane>>4, ctb=wv<<1;
  for (int i=t;i<512;i+=256){
    int row=i>>5, ch=i&31;
    uint4 u=*(const uint4*)&pooled[(((((gb<<4)+row)<<3)+hd)<<8)+(ch<<3)];
    *(uint4*)&A_lds[(row<<8)+((ch^(row&7))<<3)]=u;
  }
  __syncthreads();
  const u16* pw=packExt+(hd<<15);
  bf16x8 bw[8][2];
  #pragma unroll
  for (int kb=0;kb<8;kb++){
    bw[kb][0]=*(const bf16x8*)&pw[(kb<<12)+(ctb<<9)+(lane<<3)];
    bw[kb][1]=*(const bf16x8*)&pw[(kb<<12)+((ctb+1)<<9)+(lane<<3)];
  }
  f32x4 zero4={0.0f,0.0f,0.0f,0.0f};
  f32x4 acc[2]={zero4,zero4};
  #pragma unroll
  for (int kb=0;kb<8;kb++){
    int ch=(kb<<2)+kh;
    bf16x8 a=*(const bf16x8*)&A_lds[(r15<<8)+((ch^(r15&7))<<3)];
    acc[0]=__builtin_amdgcn_mfma_f32_16x16x32_bf16(a,bw[kb][0],acc[0],0,0,0);
    acc[1]=__builtin_amdgcn_mfma_f32_16x16x32_bf16(a,bw[kb][1],acc[1],0,0,0);
  }
  float eb[2]={ext_b[(hd<<7)+(wv<<5)+r15], ext_b[(hd<<7)+(wv<<5)+16+r15]};
  #pragma unroll
  for (int cc=0;cc<2;cc++){
    int col=(wv<<5)+(cc<<4)+r15;
    #pragma unroll
    for (int i=0;i<4;i++) zf[((kh<<2)+i)*132+col]=acc[cc][i]+eb[cc];
  }
  __syncthreads();
  int row=t>>4, q=t&15;
  const float* zr=&zf[row*132+(q<<3)];
  float s=0,ss=0;
  #pragma unroll
  for (int i=0;i<8;i++){ float v=zr[i]; s+=v; ss+=v*v; }
  s+=__shfl_xor(s,1); ss+=__shfl_xor(ss,1);
  s+=__shfl_xor(s,2); ss+=__shfl_xor(ss,2);
  s+=__shfl_xor(s,4); ss+=__shfl_xor(ss,4);
  s+=__shfl_xor(s,8); ss+=__shfl_xor(ss,8);
  float mu=s*0.0078125f, var=ss*0.0078125f-mu*mu, rstd=rsqrtf(var+1e-5f);
  const float* g=&ln_g[(hd<<7)+(q<<3)];
  const float* bb=&ln_b[(hd<<7)+(q<<3)];
  float e[8];
  #pragma unroll
  for (int i=0;i<8;i++) e[i]=fmaxf((zr[i]-mu)*rstd*g[i]+bb[i],0.0f);
  *(uint4*)&pooled[(((((gb<<4)+row)<<3)+hd)<<8)+(q<<3)]=pack8(e);
}

// ---------------- head 2: ctx = relu(mean_h(head_emb) @ hubW + b) ----------------
__global__ __launch_bounds__(256) void ctx_kernel(
  const u16* __restrict__ pooled, const u16* __restrict__ packHub,
  const float* __restrict__ hub_b, u16* __restrict__ ctx)
{
  __shared__ __align__(16) u16 m_lds[2048];   // [16][128] swizzled
  int t=threadIdx.x, gb=blockIdx.x;
  int lane=t&63, wv=t>>6, r15=lane&15, kh=lane>>4, ctb=wv<<1;
  {
    int row=t>>4, ch=t&15;
    float a8[8]={0,0,0,0,0,0,0,0};
    #pragma unroll
    for (int h=0;h<8;h++){
      uint4 u=*(const uint4*)&pooled[(((((gb<<4)+row)<<3)+h)<<8)+(ch<<3)];
      float f[8]; unpack8(u,f);
      #pragma unroll
      for (int k=0;k<8;k++) a8[k]+=f[k];
    }
    #pragma unroll
    for (int k=0;k<8;k++) a8[k]*=0.125f;
    *(uint4*)&m_lds[(row<<7)+((ch^(row&7))<<3)]=pack8(a8);
  }
  __syncthreads();
  bf16x8 bh[4][2];
  #pragma unroll
  for (int kb=0;kb<4;kb++){
    bh[kb][0]=*(const bf16x8*)&packHub[(kb<<12)+(ctb<<9)+(lane<<3)];
    bh[kb][1]=*(const bf16x8*)&packHub[(kb<<12)+((ctb+1)<<9)+(lane<<3)];
  }
  f32x4 zero4={0.0f,0.0f,0.0f,0.0f};
  f32x4 acc[2]={zero4,zero4};
  #pragma unroll
  for (int kb=0;kb<4;kb++){
    int ch=(kb<<2)+kh;
    bf16x8 a=*(const bf16x8*)&m_lds[(r15<<7)+((ch^(r15&7))<<3)];
    acc[0]=__builtin_amdgcn_mfma_f32_16x16x32_bf16(a,bh[kb][0],acc[0],0,0,0);
    acc[1]=__builtin_amdgcn_mfma_f32_16x16x32_bf16(a,bh[kb][1],acc[1],0,0,0);
  }
  float hb[2]={hub_b[(wv<<5)+r15], hub_b[(wv<<5)+16+r15]};
  #pragma unroll
  for (int cc=0;cc<2;cc++){
    int col=(wv<<5)+(cc<<4)+r15;
    #pragma unroll
    for (int i=0;i<4;i++){
      int row=(kh<<2)+i;
      ctx[(((gb<<4)+row)<<7)+col]=f2bf(fmaxf(acc[cc][i]+hb[cc],0.0f));
    }
  }
}

// ---------------- head 3: hh = relu([he|ctx]@polW1+b1); logits = hh@polW2+b2 ----------------
__global__ __launch_bounds__(256) void pol_kernel(
  const u16* __restrict__ pooled, const u16* __restrict__ ctx,
  const u16* __restrict__ packPol1, const u16* __restrict__ packPol2,
  const float* __restrict__ pol_b1, const float* __restrict__ pol_b2,
  float* __restrict__ out)
{
  __shared__ __align__(16) u16 A_lds[4096];  // [16][256]
  __shared__ __align__(16) u16 hh[2048];     // [16][128]
  int t=threadIdx.x, gb=blockIdx.x, hd=blockIdx.y;
  int lane=t&63, wv=t>>6, r15=lane&15, kh=lane>>4, ctb=wv<<1;
  for (int i=t;i<512;i+=256){
    int row=i>>5, ch=i&31;
    uint4 u;
    if (ch<16) u=*(const uint4*)&pooled[(((((gb<<4)+row)<<3)+hd)<<8)+(ch<<3)];
    else       u=*(const uint4*)&ctx[(((gb<<4)+row)<<7)+((ch-16)<<3)];
    *(uint4*)&A_lds[(row<<8)+((ch^(row&7))<<3)]=u;
  }
  __syncthreads();
  const u16* pw=packPol1+(hd<<15);
  bf16x8 bw[8][2];
  #pragma unroll
  for (int kb=0;kb<8;kb++){
    bw[kb][0]=*(const bf16x8*)&pw[(kb<<12)+(ctb<<9)+(lane<<3)];
    bw[kb][1]=*(const bf16x8*)&pw[(kb<<12)+((ctb+1)<<9)+(lane<<3)];
  }
  f32x4 zero4={0.0f,0.0f,0.0f,0.0f};
  f32x4 acc[2]={zero4,zero4};
  #pragma unroll
  for (int kb=0;kb<8;kb++){
    int ch=(kb<<2)+kh;
    bf16x8 a=*(const bf16x8*)&A_lds[(r15<<8)+((ch^(r15&7))<<3)];
    acc[0]=__builtin_amdgcn_mfma_f32_16x16x32_bf16(a,bw[kb][0],acc[0],0,0,0);
    acc[1]=__builtin_amdgcn_mfma_f32_16x16x32_bf16(a,bw[kb][1],acc[1],0,0,0);
  }
  float pb[2]={pol_b1[(hd<<7)+(wv<<5)+r15], pol_b1[(hd<<7)+(wv<<5)+16+r15]};
  #pragma unroll
  for (int cc=0;cc<2;cc++){
    int col=(wv<<5)+(cc<<4)+r15;
    #pragma unroll
    for (int i=0;i<4;i++){
      int row=(kh<<2)+i;
      float v=fmaxf(acc[cc][i]+pb[cc],0.0f);
      hh[(row<<7)+((((col>>3)^(row&7))<<3)|(col&7))]=f2bf(v);
    }
  }
  __syncthreads();
  const u16* p2=packPol2+(hd<<13);
  bf16x8 b2[4];
  #pragma unroll
  for (int kb=0;kb<4;kb++)
    b2[kb]=*(const bf16x8*)&p2[(kb<<11)+(wv<<9)+(lane<<3)];
  f32x4 a2=zero4;
  #pragma unroll
  for (int kb=0;kb<4;kb++){
    int ch=(kb<<2)+kh;
    bf16x8 a=*(const bf16x8*)&hh[(r15<<7)+((ch^(r15&7))<<3)];
    a2=__builtin_amdgcn_mfma_f32_16x16x32_bf16(a,b2[kb],a2,0,0,0);
  }
  int col=(wv<<4)+r15;
  if (col<56){
    float pb2=pol_b2[hd*56+col];
    #pragma unroll
    for (int i=0;i<4;i++){
      int row=(kh<<2)+i;
      out[(((((gb<<4)+row)<<3)+hd)*56)+col]=a2[i]+pb2;
    }
  }
}

extern "C" void kernel_launch(void* const* d_in, const int* in_sizes, int n_in,
                              void* d_out, int out_size, void* d_ws, size_t ws_size,
                              hipStream_t stream)
{
  const float* x     =(const float*)d_in[0];
  const int*   ei    =(const int*)  d_in[1];
  const int*   subs  =(const int*)  d_in[3];
  const float* W_in  =(const float*)d_in[4];
  const float* b_in  =(const float*)d_in[5];
  const float* W_self=(const float*)d_in[6];
  const float* W_nbr =(const float*)d_in[7];
  const float* b_enc =(const float*)d_in[8];
  const float* extW  =(const float*)d_in[9];
  const float* ext_b =(const float*)d_in[10];
  const float* ln_g  =(const float*)d_in[11];
  const float* ln_b  =(const float*)d_in[12];
  const float* hubW  =(const float*)d_in[13];
  const float* hub_b =(const float*)d_in[14];
  const float* polW1 =(const float*)d_in[15];
  const float* pol_b1=(const float*)d_in[16];
  const float* polW2 =(const float*)d_in[17];
  const float* pol_b2=(const float*)d_in[18];
  const float* valW1 =(const float*)d_in[19];
  const float* val_b1=(const float*)d_in[20];
  const float* valW2 =(const float*)d_in[21];
  const float* val_b2=(const float*)d_in[22];
  float* out=(float*)d_out;
  u16* ws=(u16*)d_ws;

  pack_w<<<2960,256,0,stream>>>(W_self,W_nbr,extW,polW1,polW2,hubW,valW1,W_in,ws);
  gnn_kernel<<<2048,256,0,stream>>>(x,ei,subs,b_in,b_enc,val_b1,valW2,val_b2,
      ws+GNN_E, ws+CTX_E, ws+VW1T_E, ws+POOL_E, out);
  head1_kernel<<<dim3(128,8),256,0,stream>>>(ws+POOL_E, ws+EXT_E, ext_b, ln_g, ln_b);
  ctx_kernel<<<128,256,0,stream>>>(ws+POOL_E, ws+HUB_E, hub_b, ws+CTX_E);
  pol_kernel<<<dim3(128,8),256,0,stream>>>(ws+POOL_E, ws+CTX_E, ws+POL1_E, ws+POL2_E,
      pol_b1, pol_b2, out);
}

// Round 6
// 192.344 us; speedup vs baseline: 1.3304x; 1.1342x over previous
//
#include <hip/hip_runtime.h>

#define E_TOT 1048576
#define LOGITS 917504

typedef short bf16x8 __attribute__((ext_vector_type(8)));
typedef float f32x4 __attribute__((ext_vector_type(4)));
typedef unsigned short u16;
typedef unsigned int u32;

#define DEV static __device__ __forceinline__

// manual RNE f32->bf16 (bit-proven in R1/R2)
DEV u16 f2bf(float f){ u32 u = __float_as_uint(f); return (u16)((u + 0x7fffu + ((u>>16)&1u))>>16); }
DEV u32 pack2(float a, float b){ return (u32)f2bf(a) | ((u32)f2bf(b)<<16); }
DEV float bf2f(u16 h){ return __uint_as_float(((u32)h)<<16); }
DEV void unpack8(uint4 u, float* f){
  f[0]=__uint_as_float(u.x<<16); f[1]=__uint_as_float(u.x&0xffff0000u);
  f[2]=__uint_as_float(u.y<<16); f[3]=__uint_as_float(u.y&0xffff0000u);
  f[4]=__uint_as_float(u.z<<16); f[5]=__uint_as_float(u.z&0xffff0000u);
  f[6]=__uint_as_float(u.w<<16); f[7]=__uint_as_float(u.w&0xffff0000u);
}
DEV uint4 pack8(const float* f){
  uint4 u; u.x=pack2(f[0],f[1]); u.y=pack2(f[2],f[3]); u.z=pack2(f[4],f[5]); u.w=pack2(f[6],f[7]); return u;
}

// workspace element offsets (u16 units)
#define GNN_E   0          // 4*2*128*128      = 131072
#define EXT_E   131072     // 8*256*128        = 262144
#define POL1_E  393216     // 8*256*128        = 262144
#define POL2_E  655360     // 8*128*64(pad)    = 65536
#define HUB_E   720896     // 128*128          = 16384
#define VW1T_E  737280     // 128*128          = 16384
#define POOL_E  753664     // B*8*256          = 4194304
#define CTX_E   4947968    // B*128 = 262144; first 4096 double as packed W_in
                           // (gnn reads W_in before ctx_kernel overwrites - stream ordered)

// ---------------- weight packing: 8 outputs/thread, vectorized stores ----------------
__global__ __launch_bounds__(256) void pack_w(
    const float* __restrict__ Wself, const float* __restrict__ Wnbr,
    const float* __restrict__ extW,  const float* __restrict__ polW1,
    const float* __restrict__ polW2, const float* __restrict__ hubW,
    const float* __restrict__ valW1, const float* __restrict__ W_in,
    u16* __restrict__ ws)
{
  int idx = (blockIdx.x*256 + threadIdx.x)<<3;    // 8 consecutive u16 outputs (j=0..7)
  float v[8];
  if (idx < 131072){                       // GNN W_self/W_nbr: [l][m][kb4][ct8][lane][j]
    int l = idx>>15, r = idx&32767;
    int m = (r>>14)&1, r2 = r&16383;
    int kb=(r2>>12)&3, ct=(r2>>9)&7, lane=(r2>>3)&63;
    int k0 = kb*32 + ((lane>>4)<<3), n = (ct<<4)+(lane&15);
    const float* W = m? Wnbr : Wself;
    #pragma unroll
    for (int j=0;j<8;j++) v[j]=W[(l<<14)+((k0+j)<<7)+n];
    *(uint4*)&ws[GNN_E+idx]=pack8(v);
  } else if (idx < 655360){                // extW / polW1: [h][kb8][ct8][lane][j]
    int i = idx - 131072;
    int isPol = (i >= 262144); if (isPol) i -= 262144;
    int h = i>>15, r = i&32767;
    int kb=(r>>12)&7, ct=(r>>9)&7, lane=(r>>3)&63;
    int k0 = kb*32 + ((lane>>4)<<3), n = (ct<<4)+(lane&15);
    const float* W = isPol? polW1 : extW;
    #pragma unroll
    for (int j=0;j<8;j++) v[j]=W[(h<<15)+((k0+j)<<7)+n];
    *(uint4*)&ws[(isPol?POL1_E:EXT_E)+i]=pack8(v);
  } else if (idx < 720896){                // polW2 padded 56->64: [h][kb4][ct4][lane][j]
    int i = idx - 655360;
    int h = i>>13, r = i&8191;
    int kb=(r>>11)&3, ct=(r>>9)&3, lane=(r>>3)&63;
    int k0=kb*32+((lane>>4)<<3), n=(ct<<4)+(lane&15);
    #pragma unroll
    for (int j=0;j<8;j++) v[j]=(n<56)? polW2[h*7168+(k0+j)*56+n] : 0.0f;
    *(uint4*)&ws[POL2_E+i]=pack8(v);
  } else if (idx < 737280){                // hubW: [kb4][ct8][lane][j]
    int i = idx-720896;
    int kb=(i>>12)&3, ct=(i>>9)&7, lane=(i>>3)&63;
    int k0=kb*32+((lane>>4)<<3), n=(ct<<4)+(lane&15);
    #pragma unroll
    for (int j=0;j<8;j++) v[j]=hubW[((k0+j)<<7)+n];
    *(uint4*)&ws[HUB_E+i]=pack8(v);
  } else if (idx < 753664){                // valW1 transposed: [c][k]
    int i = idx-737280;
    int c = i>>7, k0 = i&127;
    #pragma unroll
    for (int j=0;j<8;j++) v[j]=valW1[((k0+j)<<7)+c];
    *(uint4*)&ws[VW1T_E+i]=pack8(v);
  } else if (idx < 757760){                // W_in padded K 16->32: [ct8][lane][j]
    int i = idx-753664;
    int ct=(i>>9)&7, lane=(i>>3)&63;
    int k0=((lane>>4)<<3), n=(ct<<4)+(lane&15);
    #pragma unroll
    for (int j=0;j<8;j++) v[j]=(k0+j<16)? W_in[((k0+j)<<7)+n] : 0.0f;
    *(uint4*)&ws[CTX_E+i]=pack8(v);
  }
}

// epilogue: acc[4][2] -> relu(acc+bias) -> h_bf (node-major) + ht (dim-major)
DEV void epi_write(u16* h_bf, u16* ht, f32x4 (&acc)[4][2], float b0, float b1,
                   int wv, int r15, int kh)
{
  float bias[2] = {b0, b1};
  #pragma unroll
  for (int rt=0;rt<4;rt++){
    int sch = (rt<<1)+(kh>>1);
    int r0  = (rt<<4)+(kh<<2);
    #pragma unroll
    for (int cc=0;cc<2;cc++){
      int col=(wv<<5)+(cc<<4)+r15;
      float v0=fmaxf(acc[rt][cc][0]+bias[cc],0.0f);
      float v1=fmaxf(acc[rt][cc][1]+bias[cc],0.0f);
      float v2=fmaxf(acc[rt][cc][2]+bias[cc],0.0f);
      float v3=fmaxf(acc[rt][cc][3]+bias[cc],0.0f);
      int chc=(col>>3);
      h_bf[((r0+0)<<7)+(((chc^((r0+0)&7))<<3)|(col&7))]=f2bf(v0);
      h_bf[((r0+1)<<7)+(((chc^((r0+1)&7))<<3)|(col&7))]=f2bf(v1);
      h_bf[((r0+2)<<7)+(((chc^((r0+2)&7))<<3)|(col&7))]=f2bf(v2);
      h_bf[((r0+3)<<7)+(((chc^((r0+3)&7))<<3)|(col&7))]=f2bf(v3);
      uint2 w; w.x=pack2(v0,v1); w.y=pack2(v2,v3);
      *(uint2*)&ht[(col<<6)+(((sch^(col&7))<<3)|((kh&1)<<2))]=w;
    }
  }
}

// ---------------- fused per-graph GNN + pooling + value head ----------------
__global__ __launch_bounds__(256,3) void gnn_kernel(
  const float* __restrict__ x, const int* __restrict__ ei,
  const int* __restrict__ subsets, const float* __restrict__ b_in,
  const float* __restrict__ b_enc, const float* __restrict__ val_b1,
  const float* __restrict__ val_W2, const float* __restrict__ val_b2,
  const u16* __restrict__ packGNN, const u16* __restrict__ packWIN,
  const u16* __restrict__ valW1T,
  u16* __restrict__ pooled, float* __restrict__ out)
{
  __shared__ __align__(16) u16 h_bf[8192];    // h  [64 node][128 dim] swizzled
  __shared__ __align__(16) u16 ht[8192];      // hT [128 dim][64 node] swizzled; alias: u32 cnt[4096]
  __shared__ __align__(16) u16 agg_bf[8192];  // agg [64][128] swizzled; alias: bf16 x tile
  __shared__ float deg_inv[64];
  __shared__ int subs_s[64];
  __shared__ float gmbuf[128];
  __shared__ float redbuf[4];

  int t=threadIdx.x, b=blockIdx.x;
  int lane=t&63, wv=t>>6, r15=lane&15, kh=lane>>4, ctb=wv<<1;
  u32* cnt=(u32*)ht;
  f32x4 zero4={0.0f,0.0f,0.0f,0.0f};

  // ---- edges -> count matrix (swizzled [dst][src]) ----
  int e0=(b<<9)+(t<<1);
  int2 sp=*(const int2*)&ei[e0];
  int2 dp=*(const int2*)&ei[E_TOT+e0];
  int s0=sp.x&63, s1=sp.y&63, d0=dp.x&63, d1=dp.y&63;
  if (t<64) subs_s[t]=subsets[t];
  for (int i=t;i<1024;i+=256) ((uint4*)cnt)[i]=make_uint4(0,0,0,0);
  __syncthreads();
  atomicAdd(&cnt[(d0<<6)+((((s0>>3)^(d0&7))<<3)|(s0&7))],1u);
  atomicAdd(&cnt[(d1<<6)+((((s1>>3)^(d1&7))<<3)|(s1&7))],1u);
  __syncthreads();
  if (t<64){
    u32 s=0;
    for (int k2=0;k2<16;k2++){ uint4 vv=((uint4*)cnt)[(t<<4)+k2]; s+=vv.x+vv.y+vv.z+vv.w; }
    deg_inv[t]=1.0f/(float)(s>0u?s:1u);
  }
  __syncthreads();

  // ---- adjacency^T B-fragments (held all 4 layers): A^T[src][dst]=cnt/deg ----
  bf16x8 adjf[4][2];
  #pragma unroll
  for (int ct=0;ct<4;ct++){
    int dst=(ct<<4)+r15; float di=deg_inv[dst];
    #pragma unroll
    for (int kb=0;kb<2;kb++){
      int cb=(kb<<2)+kh;
      const u32* p=&cnt[(dst<<6)+((cb^(dst&7))<<3)];
      uint4 lo=*(const uint4*)p, hi=*(const uint4*)(p+4);
      uint4 pk;
      pk.x=pack2((float)lo.x*di,(float)lo.y*di);
      pk.y=pack2((float)lo.z*di,(float)lo.w*di);
      pk.z=pack2((float)hi.x*di,(float)hi.y*di);
      pk.w=pack2((float)hi.z*di,(float)hi.w*di);
      adjf[ct][kb]=*(bf16x8*)&pk;
    }
  }

  // ---- stage x bf16 [64][32] (K padded) into agg area, vectorized ----
  u16* xb=agg_bf;
  { int row=t>>2, c0=(t&3)<<3;
    float v[8];
    if (c0<16){
      const float* xg=x+(b<<10)+(row<<4)+c0;
      #pragma unroll
      for (int j=0;j<8;j++) v[j]=xg[j];
    } else {
      #pragma unroll
      for (int j=0;j<8;j++) v[j]=0.0f;
    }
    *(uint4*)&xb[(row<<5)+((((c0>>3)^(row&3))<<3))]=pack8(v);
  }
  __syncthreads();   // cnt reads (adjf) done + xb staged

  // ---- h0 = relu(x @ W_in + b_in) via MFMA (reads xb inline; writes h_bf/ht) ----
  {
    bf16x8 bw0=*(const bf16x8*)&packWIN[(ctb<<9)+(lane<<3)];
    bf16x8 bw1=*(const bf16x8*)&packWIN[((ctb+1)<<9)+(lane<<3)];
    f32x4 acc[4][2];
    #pragma unroll
    for (int rt=0;rt<4;rt++){ acc[rt][0]=zero4; acc[rt][1]=zero4; }
    #pragma unroll
    for (int rt=0;rt<4;rt++){
      int row=(rt<<4)+r15;
      bf16x8 af=*(const bf16x8*)&xb[(row<<5)+((kh^(row&3))<<3)];
      acc[rt][0]=__builtin_amdgcn_mfma_f32_16x16x32_bf16(af,bw0,acc[rt][0],0,0,0);
      acc[rt][1]=__builtin_amdgcn_mfma_f32_16x16x32_bf16(af,bw1,acc[rt][1],0,0,0);
    }
    float bi0=b_in[(wv<<5)+r15], bi1=b_in[(wv<<5)+16+r15];
    epi_write(h_bf,ht,acc,bi0,bi1,wv,r15,kh);
  }
  __syncthreads();

  // ---- 4 GNN layers ----
  #pragma unroll 1
  for (int l=0;l<4;l++){
    const u16* pl = packGNN + (l<<15);
    // phase A: aggT[dim][node] = hT @ adjT (reads ht, writes agg_bf - separate buffers)
    f32x4 a2[2][4];
    #pragma unroll
    for (int rt=0;rt<2;rt++){ a2[rt][0]=zero4; a2[rt][1]=zero4; a2[rt][2]=zero4; a2[rt][3]=zero4; }
    #pragma unroll
    for (int kb=0;kb<2;kb++){
      #pragma unroll
      for (int rt=0;rt<2;rt++){
        int dim=((ctb+rt)<<4)+r15;
        bf16x8 af=*(const bf16x8*)&ht[(dim<<6)+((((kb<<2)+kh)^(dim&7))<<3)];
        #pragma unroll
        for (int ct=0;ct<4;ct++)
          a2[rt][ct]=__builtin_amdgcn_mfma_f32_16x16x32_bf16(af,adjf[ct][kb],a2[rt][ct],0,0,0);
      }
    }
    #pragma unroll
    for (int rt=0;rt<2;rt++){
      int dch=((ctb+rt)<<1)+(kh>>1);
      #pragma unroll
      for (int ct=0;ct<4;ct++){
        int node=(ct<<4)+r15;
        uint2 w; w.x=pack2(a2[rt][ct][0],a2[rt][ct][1]); w.y=pack2(a2[rt][ct][2],a2[rt][ct][3]);
        *(uint2*)&agg_bf[(node<<7)+(((dch^(node&7))<<3)|((kh&1)<<2))]=w;
      }
    }
    __syncthreads();   // agg ready (also guards xb overwrite vs h0 reads on l==0)
    // phase B: h_new = relu(h@Wself + agg@Wnbr + b_enc); weights streamed per-kb
    f32x4 acc[4][2];
    #pragma unroll
    for (int rt=0;rt<4;rt++){ acc[rt][0]=zero4; acc[rt][1]=zero4; }
    #pragma unroll 2
    for (int kb=0;kb<4;kb++){
      int ch=(kb<<2)+kh;
      bf16x8 bs0=*(const bf16x8*)&pl[(kb<<12)+(ctb<<9)+(lane<<3)];
      bf16x8 bs1=*(const bf16x8*)&pl[(kb<<12)+((ctb+1)<<9)+(lane<<3)];
      bf16x8 bn0=*(const bf16x8*)&pl[16384+(kb<<12)+(ctb<<9)+(lane<<3)];
      bf16x8 bn1=*(const bf16x8*)&pl[16384+(kb<<12)+((ctb+1)<<9)+(lane<<3)];
      #pragma unroll
      for (int rt=0;rt<4;rt++){
        int row=(rt<<4)+r15;
        bf16x8 af=*(const bf16x8*)&h_bf[(row<<7)+((ch^(row&7))<<3)];
        acc[rt][0]=__builtin_amdgcn_mfma_f32_16x16x32_bf16(af,bs0,acc[rt][0],0,0,0);
        acc[rt][1]=__builtin_amdgcn_mfma_f32_16x16x32_bf16(af,bs1,acc[rt][1],0,0,0);
      }
      #pragma unroll
      for (int rt=0;rt<4;rt++){
        int row=(rt<<4)+r15;
        bf16x8 ag=*(const bf16x8*)&agg_bf[(row<<7)+((ch^(row&7))<<3)];
        acc[rt][0]=__builtin_amdgcn_mfma_f32_16x16x32_bf16(ag,bn0,acc[rt][0],0,0,0);
        acc[rt][1]=__builtin_amdgcn_mfma_f32_16x16x32_bf16(ag,bn1,acc[rt][1],0,0,0);
      }
    }
    float be0=b_enc[(l<<7)+(wv<<5)+r15], be1=b_enc[(l<<7)+(wv<<5)+16+r15];
    __syncthreads();   // all h_bf/agg reads done before epilogue overwrites h_bf/ht
    epi_write(h_bf,ht,acc,be0,be1,wv,r15,kh);
    __syncthreads();
  }

  // ---- pooling: per head mean/max over its 8 subset nodes ----
  {
    int hd=t>>5, q=t&31, cb=q<<2;
    float ms[4]={0,0,0,0}, mx[4]={-3e38f,-3e38f,-3e38f,-3e38f};
    int ch=cb>>3;
    #pragma unroll
    for (int s=0;s<8;s++){
      int row=subs_s[(hd<<3)+s]; int sw=row&7;
      uint2 u=*(const uint2*)&h_bf[(row<<7)+(((ch^sw)<<3)|(cb&7))];
      float f0=__uint_as_float(u.x<<16), f1=__uint_as_float(u.x&0xffff0000u);
      float f2=__uint_as_float(u.y<<16), f3=__uint_as_float(u.y&0xffff0000u);
      ms[0]+=f0; ms[1]+=f1; ms[2]+=f2; ms[3]+=f3;
      mx[0]=fmaxf(mx[0],f0); mx[1]=fmaxf(mx[1],f1);
      mx[2]=fmaxf(mx[2],f2); mx[3]=fmaxf(mx[3],f3);
    }
    int base=(((b<<3)+hd)<<8);
    uint2 um,ux;
    um.x=pack2(ms[0]*0.125f,ms[1]*0.125f); um.y=pack2(ms[2]*0.125f,ms[3]*0.125f);
    ux.x=pack2(mx[0],mx[1]);               ux.y=pack2(mx[2],mx[3]);
    *(uint2*)&pooled[base+cb]    =um;
    *(uint2*)&pooled[base+128+cb]=ux;
  }

  // ---- value head: gm from ht rows (full 64-node sum, order-free) ----
  float gsum=0.0f;
  if (t<128){
    #pragma unroll
    for (int c=0;c<8;c++){
      uint4 u=*(const uint4*)&ht[(t<<6)+(c<<3)];
      float f[8]; unpack8(u,f);
      gsum+=f[0]+f[1]+f[2]+f[3]+f[4]+f[5]+f[6]+f[7];
    }
  }
  __syncthreads();
  if (t<128) gmbuf[t]=gsum*0.015625f;
  __syncthreads();
  if (t<128){
    float acc=val_b1[t];
    const uint4* wr=(const uint4*)&valW1T[t<<7];
    #pragma unroll
    for (int c=0;c<16;c++){
      uint4 u=wr[c]; float f[8]; unpack8(u,f);
      const float* gp=&gmbuf[c<<3];
      #pragma unroll
      for (int j=0;j<8;j++) acc=fmaf(gp[j],f[j],acc);
    }
    float contrib=fmaxf(acc,0.0f)*val_W2[t];
    #pragma unroll
    for (int d=1;d<64;d<<=1) contrib+=__shfl_xor(contrib,d);
    if (lane==0) redbuf[wv]=contrib;
  }
  __syncthreads();
  if (t==0) out[LOGITS+b]=tanhf(redbuf[0]+redbuf[1]+val_b2[0]);
}

// ---------------- head 1: z = pooled@extW + b, LayerNorm, relu (16 graphs/block) ----------------
__global__ __launch_bounds__(256) void head1_kernel(
  u16* __restrict__ pooled, const u16* __restrict__ packExt,
  const float* __restrict__ ext_b, const float* __restrict__ ln_g,
  const float* __restrict__ ln_b)
{
  __shared__ __align__(16) u16 A_lds[4096];   // [16][256] swizzled
  __shared__ float zf[16*132];
  int t=threadIdx.x, gb=blockIdx.x, hd=blockIdx.y;
  int lane=t&63, wv=t>>6, r15=lane&15, kh=lane>>4, ctb=wv<<1;
  for (int i=t;i<512;i+=256){
    int row=i>>5, ch=i&31;
    uint4 u=*(const uint4*)&pooled[(((((gb<<4)+row)<<3)+hd)<<8)+(ch<<3)];
    *(uint4*)&A_lds[(row<<8)+((ch^(row&7))<<3)]=u;
  }
  __syncthreads();
  const u16* pw=packExt+(hd<<15);
  bf16x8 bw[8][2];
  #pragma unroll
  for (int kb=0;kb<8;kb++){
    bw[kb][0]=*(const bf16x8*)&pw[(kb<<12)+(ctb<<9)+(lane<<3)];
    bw[kb][1]=*(const bf16x8*)&pw[(kb<<12)+((ctb+1)<<9)+(lane<<3)];
  }
  f32x4 zero4={0.0f,0.0f,0.0f,0.0f};
  f32x4 acc[2]={zero4,zero4};
  #pragma unroll
  for (int kb=0;kb<8;kb++){
    int ch=(kb<<2)+kh;
    bf16x8 a=*(const bf16x8*)&A_lds[(r15<<8)+((ch^(r15&7))<<3)];
    acc[0]=__builtin_amdgcn_mfma_f32_16x16x32_bf16(a,bw[kb][0],acc[0],0,0,0);
    acc[1]=__builtin_amdgcn_mfma_f32_16x16x32_bf16(a,bw[kb][1],acc[1],0,0,0);
  }
  float eb[2]={ext_b[(hd<<7)+(wv<<5)+r15], ext_b[(hd<<7)+(wv<<5)+16+r15]};
  #pragma unroll
  for (int cc=0;cc<2;cc++){
    int col=(wv<<5)+(cc<<4)+r15;
    #pragma unroll
    for (int i=0;i<4;i++) zf[((kh<<2)+i)*132+col]=acc[cc][i]+eb[cc];
  }
  __syncthreads();
  int row=t>>4, q=t&15;
  const float* zr=&zf[row*132+(q<<3)];
  float s=0,ss=0;
  #pragma unroll
  for (int i=0;i<8;i++){ float v=zr[i]; s+=v; ss+=v*v; }
  s+=__shfl_xor(s,1); ss+=__shfl_xor(ss,1);
  s+=__shfl_xor(s,2); ss+=__shfl_xor(ss,2);
  s+=__shfl_xor(s,4); ss+=__shfl_xor(ss,4);
  s+=__shfl_xor(s,8); ss+=__shfl_xor(ss,8);
  float mu=s*0.0078125f, var=ss*0.0078125f-mu*mu, rstd=rsqrtf(var+1e-5f);
  const float* g=&ln_g[(hd<<7)+(q<<3)];
  const float* bb=&ln_b[(hd<<7)+(q<<3)];
  float e[8];
  #pragma unroll
  for (int i=0;i<8;i++) e[i]=fmaxf((zr[i]-mu)*rstd*g[i]+bb[i],0.0f);
  *(uint4*)&pooled[(((((gb<<4)+row)<<3)+hd)<<8)+(q<<3)]=pack8(e);
}

// ---------------- head 2: ctx = relu(mean_h(head_emb) @ hubW + b) ----------------
__global__ __launch_bounds__(256) void ctx_kernel(
  const u16* __restrict__ pooled, const u16* __restrict__ packHub,
  const float* __restrict__ hub_b, u16* __restrict__ ctx)
{
  __shared__ __align__(16) u16 m_lds[2048];   // [16][128] swizzled
  int t=threadIdx.x, gb=blockIdx.x;
  int lane=t&63, wv=t>>6, r15=lane&15, kh=lane>>4, ctb=wv<<1;
  {
    int row=t>>4, ch=t&15;
    float a8[8]={0,0,0,0,0,0,0,0};
    #pragma unroll
    for (int h=0;h<8;h++){
      uint4 u=*(const uint4*)&pooled[(((((gb<<4)+row)<<3)+h)<<8)+(ch<<3)];
      float f[8]; unpack8(u,f);
      #pragma unroll
      for (int k=0;k<8;k++) a8[k]+=f[k];
    }
    #pragma unroll
    for (int k=0;k<8;k++) a8[k]*=0.125f;
    *(uint4*)&m_lds[(row<<7)+((ch^(row&7))<<3)]=pack8(a8);
  }
  __syncthreads();
  bf16x8 bh[4][2];
  #pragma unroll
  for (int kb=0;kb<4;kb++){
    bh[kb][0]=*(const bf16x8*)&packHub[(kb<<12)+(ctb<<9)+(lane<<3)];
    bh[kb][1]=*(const bf16x8*)&packHub[(kb<<12)+((ctb+1)<<9)+(lane<<3)];
  }
  f32x4 zero4={0.0f,0.0f,0.0f,0.0f};
  f32x4 acc[2]={zero4,zero4};
  #pragma unroll
  for (int kb=0;kb<4;kb++){
    int ch=(kb<<2)+kh;
    bf16x8 a=*(const bf16x8*)&m_lds[(r15<<7)+((ch^(r15&7))<<3)];
    acc[0]=__builtin_amdgcn_mfma_f32_16x16x32_bf16(a,bh[kb][0],acc[0],0,0,0);
    acc[1]=__builtin_amdgcn_mfma_f32_16x16x32_bf16(a,bh[kb][1],acc[1],0,0,0);
  }
  float hb[2]={hub_b[(wv<<5)+r15], hub_b[(wv<<5)+16+r15]};
  #pragma unroll
  for (int cc=0;cc<2;cc++){
    int col=(wv<<5)+(cc<<4)+r15;
    #pragma unroll
    for (int i=0;i<4;i++){
      int row=(kh<<2)+i;
      ctx[(((gb<<4)+row)<<7)+col]=f2bf(fmaxf(acc[cc][i]+hb[cc],0.0f));
    }
  }
}

// ---------------- head 3: hh = relu([he|ctx]@polW1+b1); logits = hh@polW2+b2 ----------------
__global__ __launch_bounds__(256) void pol_kernel(
  const u16* __restrict__ pooled, const u16* __restrict__ ctx,
  const u16* __restrict__ packPol1, const u16* __restrict__ packPol2,
  const float* __restrict__ pol_b1, const float* __restrict__ pol_b2,
  float* __restrict__ out)
{
  __shared__ __align__(16) u16 A_lds[4096];  // [16][256]
  __shared__ __align__(16) u16 hh[2048];     // [16][128]
  int t=threadIdx.x, gb=blockIdx.x, hd=blockIdx.y;
  int lane=t&63, wv=t>>6, r15=lane&15, kh=lane>>4, ctb=wv<<1;
  for (int i=t;i<512;i+=256){
    int row=i>>5, ch=i&31;
    uint4 u;
    if (ch<16) u=*(const uint4*)&pooled[(((((gb<<4)+row)<<3)+hd)<<8)+(ch<<3)];
    else       u=*(const uint4*)&ctx[(((gb<<4)+row)<<7)+((ch-16)<<3)];
    *(uint4*)&A_lds[(row<<8)+((ch^(row&7))<<3)]=u;
  }
  __syncthreads();
  const u16* pw=packPol1+(hd<<15);
  bf16x8 bw[8][2];
  #pragma unroll
  for (int kb=0;kb<8;kb++){
    bw[kb][0]=*(const bf16x8*)&pw[(kb<<12)+(ctb<<9)+(lane<<3)];
    bw[kb][1]=*(const bf16x8*)&pw[(kb<<12)+((ctb+1)<<9)+(lane<<3)];
  }
  f32x4 zero4={0.0f,0.0f,0.0f,0.0f};
  f32x4 acc[2]={zero4,zero4};
  #pragma unroll
  for (int kb=0;kb<8;kb++){
    int ch=(kb<<2)+kh;
    bf16x8 a=*(const bf16x8*)&A_lds[(r15<<8)+((ch^(r15&7))<<3)];
    acc[0]=__builtin_amdgcn_mfma_f32_16x16x32_bf16(a,bw[kb][0],acc[0],0,0,0);
    acc[1]=__builtin_amdgcn_mfma_f32_16x16x32_bf16(a,bw[kb][1],acc[1],0,0,0);
  }
  float pb[2]={pol_b1[(hd<<7)+(wv<<5)+r15], pol_b1[(hd<<7)+(wv<<5)+16+r15]};
  #pragma unroll
  for (int cc=0;cc<2;cc++){
    int col=(wv<<5)+(cc<<4)+r15;
    #pragma unroll
    for (int i=0;i<4;i++){
      int row=(kh<<2)+i;
      float v=fmaxf(acc[cc][i]+pb[cc],0.0f);
      hh[(row<<7)+((((col>>3)^(row&7))<<3)|(col&7))]=f2bf(v);
    }
  }
  __syncthreads();
  const u16* p2=packPol2+(hd<<13);
  bf16x8 b2[4];
  #pragma unroll
  for (int kb=0;kb<4;kb++)
    b2[kb]=*(const bf16x8*)&p2[(kb<<11)+(wv<<9)+(lane<<3)];
  f32x4 a2=zero4;
  #pragma unroll
  for (int kb=0;kb<4;kb++){
    int ch=(kb<<2)+kh;
    bf16x8 a=*(const bf16x8*)&hh[(r15<<7)+((ch^(r15&7))<<3)];
    a2=__builtin_amdgcn_mfma_f32_16x16x32_bf16(a,b2[kb],a2,0,0,0);
  }
  int col=(wv<<4)+r15;
  if (col<56){
    float pb2=pol_b2[hd*56+col];
    #pragma unroll
    for (int i=0;i<4;i++){
      int row=(kh<<2)+i;
      out[(((((gb<<4)+row)<<3)+hd)*56)+col]=a2[i]+pb2;
    }
  }
}

extern "C" void kernel_launch(void* const* d_in, const int* in_sizes, int n_in,
                              void* d_out, int out_size, void* d_ws, size_t ws_size,
                              hipStream_t stream)
{
  const float* x     =(const float*)d_in[0];
  const int*   ei    =(const int*)  d_in[1];
  const int*   subs  =(const int*)  d_in[3];
  const float* W_in  =(const float*)d_in[4];
  const float* b_in  =(const float*)d_in[5];
  const float* W_self=(const float*)d_in[6];
  const float* W_nbr =(const float*)d_in[7];
  const float* b_enc =(const float*)d_in[8];
  const float* extW  =(const float*)d_in[9];
  const float* ext_b =(const float*)d_in[10];
  const float* ln_g  =(const float*)d_in[11];
  const float* ln_b  =(const float*)d_in[12];
  const float* hubW  =(const float*)d_in[13];
  const float* hub_b =(const float*)d_in[14];
  const float* polW1 =(const float*)d_in[15];
  const float* pol_b1=(const float*)d_in[16];
  const float* polW2 =(const float*)d_in[17];
  const float* pol_b2=(const float*)d_in[18];
  const float* valW1 =(const float*)d_in[19];
  const float* val_b1=(const float*)d_in[20];
  const float* valW2 =(const float*)d_in[21];
  const float* val_b2=(const float*)d_in[22];
  float* out=(float*)d_out;
  u16* ws=(u16*)d_ws;

  pack_w<<<370,256,0,stream>>>(W_self,W_nbr,extW,polW1,polW2,hubW,valW1,W_in,ws);
  gnn_kernel<<<2048,256,0,stream>>>(x,ei,subs,b_in,b_enc,val_b1,valW2,val_b2,
      ws+GNN_E, ws+CTX_E, ws+VW1T_E, ws+POOL_E, out);
  head1_kernel<<<dim3(128,8),256,0,stream>>>(ws+POOL_E, ws+EXT_E, ext_b, ln_g, ln_b);
  ctx_kernel<<<128,256,0,stream>>>(ws+POOL_E, ws+HUB_E, hub_b, ws+CTX_E);
  pol_kernel<<<dim3(128,8),256,0,stream>>>(ws+POOL_E, ws+CTX_E, ws+POL1_E, ws+POL2_E,
      pol_b1, pol_b2, out);
}